// Round 2
// baseline (97.372 us; speedup 1.0000x reference)
//
#include <hip/hip_runtime.h>

// Problem dims (fixed by the reference):
//   x1, x2: (B=8, C=64, H=256, W=256) fp32
//   out:    (8, 128, 256, 256) fp32 = concat([x_rec, x2], axis=1)
//
// NOTE on fp ordering: the harness validates against a numpy translation of
// the jax reference, elementwise f32, left-to-right. The _ffm mask
// (|v1| >= |v2|) is discontinuous — a 1-ulp difference in B/C/D can flip the
// selection and produce an O(1) output delta. So every expression below
// replicates the reference's exact binary-op order:
//   x1_1=p/2, x2_1=r/2, x1_2=q/2, x2_2=s/2   (p=ee q=eo r=oe s=oo pixel)
//   A = ((x1_1 + x2_1) + x1_2) + x2_2
//   B = ((-x1_1 - x2_1) + x1_2) + x2_2
//   C = ((-x1_1 + x2_1) - x1_2) + x2_2
//   D = ((x1_1 - x2_1) - x1_2) + x2_2
//   fa = (A1 + A2) / 2 ; f{b,c,d} = |v1|>=|v2| ? v1 : v2  (exact select)
//   out_ee = (((fa - fb) - fc) + fd) * 0.5f   // (../4)*2, both scalings exact
//   out_oe = (((fa - fb) + fc) - fd) * 0.5f
//   out_eo = (((fa + fb) - fc) - fd) * 0.5f
//   out_oo = (((fa + fb) + fc) + fd) * 0.5f
// All multiplies are by powers of two (exact), so ffp-contract fma fusion
// cannot perturb any rounding; C++ without fast-math forbids reassociation.

__device__ __forceinline__ void haar_ref_order(float p, float q, float r, float s,
                                               float& A, float& B, float& C, float& D) {
    const float p2 = p * 0.5f;
    const float q2 = q * 0.5f;
    const float r2 = r * 0.5f;
    const float s2 = s * 0.5f;
    A = ((p2 + r2) + q2) + s2;
    B = (((-p2) - r2) + q2) + s2;
    C = (((-p2) + r2) - q2) + s2;
    D = ((p2 - r2) - q2) + s2;
}

__device__ __forceinline__ float ffm(float a, float b) {
    return (fabsf(a) >= fabsf(b)) ? a : b;
}

__device__ __forceinline__ void fuse_idwt(float A1, float B1, float C1, float D1,
                                          float A2, float B2, float C2, float D2,
                                          float& oee, float& oeo, float& ooe, float& oos) {
    const float fa = (A1 + A2) * 0.5f;
    const float fb = ffm(B1, B2);
    const float fc = ffm(C1, C2);
    const float fd = ffm(D1, D2);
    oee = (((fa - fb) - fc) + fd) * 0.5f;  // even row, even col
    ooe = (((fa - fb) + fc) - fd) * 0.5f;  // odd  row, even col
    oeo = (((fa + fb) - fc) - fd) * 0.5f;  // even row, odd col
    oos = (((fa + fb) + fc) + fd) * 0.5f;  // odd  row, odd col
}

__global__ __launch_bounds__(256)
void dwt_fuse_idwt_concat_kernel(const float* __restrict__ x1,
                                 const float* __restrict__ x2,
                                 float* __restrict__ out) {
    // One thread handles 2 rows x 4 cols: two adjacent 2x2 blocks.
    // idx -> (bc, hp, w4); W/4 = 64 float4-cols, H/2 = 128 row-pairs,
    // bc in [0, 8*64). Total threads = 512*128*64 = 4,194,304.
    const int idx = blockIdx.x * blockDim.x + threadIdx.x;

    const int w4 = idx & 63;         // float4 column index
    const int t  = idx >> 6;
    const int hp = t & 127;          // row-pair index
    const int bc = t >> 7;           // b*64 + c, in [0, 512)

    // input base: element offset of (bc, 2*hp, 4*w4); row stride = 256 floats
    const int inBase = ((bc << 8) + (hp << 1)) * 256 + (w4 << 2);

    const float4 a0 = *reinterpret_cast<const float4*>(x1 + inBase);        // x1 even row
    const float4 a1 = *reinterpret_cast<const float4*>(x1 + inBase + 256);  // x1 odd row
    const float4 b0 = *reinterpret_cast<const float4*>(x2 + inBase);        // x2 even row
    const float4 b1 = *reinterpret_cast<const float4*>(x2 + inBase + 256);  // x2 odd row

    float4 o0, o1;  // reconstructed even/odd rows

    // ---- block 0: cols (0,1) of the float4 ----
    {
        float A1, B1, C1, D1, A2, B2, C2, D2;
        haar_ref_order(a0.x, a0.y, a1.x, a1.y, A1, B1, C1, D1);
        haar_ref_order(b0.x, b0.y, b1.x, b1.y, A2, B2, C2, D2);
        fuse_idwt(A1, B1, C1, D1, A2, B2, C2, D2, o0.x, o0.y, o1.x, o1.y);
    }
    // ---- block 1: cols (2,3) of the float4 ----
    {
        float A1, B1, C1, D1, A2, B2, C2, D2;
        haar_ref_order(a0.z, a0.w, a1.z, a1.w, A1, B1, C1, D1);
        haar_ref_order(b0.z, b0.w, b1.z, b1.w, A2, B2, C2, D2);
        fuse_idwt(A1, B1, C1, D1, A2, B2, C2, D2, o0.z, o0.w, o1.z, o1.w);
    }

    // output: (8, 128, 256, 256); x_rec at channel c, x2 copy at channel 64+c
    const int b = bc >> 6;
    const int c = bc & 63;
    const int outBaseRec = ((((b << 7) + c) << 8) | (hp << 1)) * 256 + (w4 << 2);
    const int outBaseCpy = outBaseRec + (64 << 16);  // +64 channels * 256*256

    *reinterpret_cast<float4*>(out + outBaseRec)        = o0;
    *reinterpret_cast<float4*>(out + outBaseRec + 256)  = o1;
    *reinterpret_cast<float4*>(out + outBaseCpy)        = b0;  // x2 copy, even row
    *reinterpret_cast<float4*>(out + outBaseCpy + 256)  = b1;  // x2 copy, odd row
}

extern "C" void kernel_launch(void* const* d_in, const int* in_sizes, int n_in,
                              void* d_out, int out_size, void* d_ws, size_t ws_size,
                              hipStream_t stream) {
    const float* x1 = (const float*)d_in[0];
    const float* x2 = (const float*)d_in[1];
    float* out = (float*)d_out;

    const int total_threads = 8 * 64 * 128 * 64;  // 4,194,304
    const int block = 256;
    const int grid = total_threads / block;       // 16384

    dwt_fuse_idwt_concat_kernel<<<grid, block, 0, stream>>>(x1, x2, out);
}

// Round 4
// 90.616 us; speedup vs baseline: 1.0745x; 1.0745x over previous
//
#include <hip/hip_runtime.h>

// Problem dims (fixed by the reference):
//   x1, x2: (B=8, C=64, H=256, W=256) fp32
//   out:    (8, 128, 256, 256) fp32 = concat([x_rec, x2], axis=1)
//
// NOTE on fp ordering: the harness validates against a numpy translation of
// the jax reference, elementwise f32, left-to-right. The _ffm mask
// (|v1| >= |v2|) is discontinuous — a 1-ulp difference in B/C/D can flip the
// selection and produce an O(1) output delta. So every expression below
// replicates the reference's exact binary-op order (verified passing, r2,
// absmax = 0.0):
//   x1_1=p/2, x2_1=r/2, x1_2=q/2, x2_2=s/2   (p=ee q=eo r=oe s=oo pixel)
//   A = ((x1_1 + x2_1) + x1_2) + x2_2
//   B = ((-x1_1 - x2_1) + x1_2) + x2_2
//   C = ((-x1_1 + x2_1) - x1_2) + x2_2
//   D = ((x1_1 - x2_1) - x1_2) + x2_2
//   fa = (A1 + A2) / 2 ; f{b,c,d} = |v1|>=|v2| ? v1 : v2  (exact select)
//   out_ee = (((fa - fb) - fc) + fd) * 0.5f
//   out_oe = (((fa - fb) + fc) - fd) * 0.5f
//   out_eo = (((fa + fb) - fc) - fd) * 0.5f
//   out_oo = (((fa + fb) + fc) + fd) * 0.5f
// All multiplies are powers of two (exact); no fast-math reassociation.

// Native clang vector type — __builtin_nontemporal_* requires scalar or
// native-vector pointee (HIP_vector_type float4 is a struct and rejected).
typedef float f32x4 __attribute__((ext_vector_type(4)));

__device__ __forceinline__ void haar_ref_order(float p, float q, float r, float s,
                                               float& A, float& B, float& C, float& D) {
    const float p2 = p * 0.5f;
    const float q2 = q * 0.5f;
    const float r2 = r * 0.5f;
    const float s2 = s * 0.5f;
    A = ((p2 + r2) + q2) + s2;
    B = (((-p2) - r2) + q2) + s2;
    C = (((-p2) + r2) - q2) + s2;
    D = ((p2 - r2) - q2) + s2;
}

__device__ __forceinline__ float ffm(float a, float b) {
    return (fabsf(a) >= fabsf(b)) ? a : b;
}

__device__ __forceinline__ void fuse_idwt(float A1, float B1, float C1, float D1,
                                          float A2, float B2, float C2, float D2,
                                          float& oee, float& oeo, float& ooe, float& oos) {
    const float fa = (A1 + A2) * 0.5f;
    const float fb = ffm(B1, B2);
    const float fc = ffm(C1, C2);
    const float fd = ffm(D1, D2);
    oee = (((fa - fb) - fc) + fd) * 0.5f;  // even row, even col
    ooe = (((fa - fb) + fc) - fd) * 0.5f;  // odd  row, even col
    oeo = (((fa + fb) - fc) - fd) * 0.5f;  // even row, odd col
    oos = (((fa + fb) + fc) + fd) * 0.5f;  // odd  row, odd col
}

__device__ __forceinline__ f32x4 ntload4(const float* p) {
    return __builtin_nontemporal_load(reinterpret_cast<const f32x4*>(p));
}
__device__ __forceinline__ void ntstore4(float* p, f32x4 v) {
    __builtin_nontemporal_store(v, reinterpret_cast<f32x4*>(p));
}

// Process one row-pair (2 rows x 4 cols = two 2x2 blocks) given the four
// input f32x4s; returns the two reconstructed output rows.
__device__ __forceinline__ void process_rowpair(f32x4 a0, f32x4 a1,
                                                f32x4 b0, f32x4 b1,
                                                f32x4& o0, f32x4& o1) {
    {
        float A1, B1, C1, D1, A2, B2, C2, D2;
        haar_ref_order(a0.x, a0.y, a1.x, a1.y, A1, B1, C1, D1);
        haar_ref_order(b0.x, b0.y, b1.x, b1.y, A2, B2, C2, D2);
        float oee, oeo, ooe, oos;
        fuse_idwt(A1, B1, C1, D1, A2, B2, C2, D2, oee, oeo, ooe, oos);
        o0.x = oee; o0.y = oeo; o1.x = ooe; o1.y = oos;
    }
    {
        float A1, B1, C1, D1, A2, B2, C2, D2;
        haar_ref_order(a0.z, a0.w, a1.z, a1.w, A1, B1, C1, D1);
        haar_ref_order(b0.z, b0.w, b1.z, b1.w, A2, B2, C2, D2);
        float oee, oeo, ooe, oos;
        fuse_idwt(A1, B1, C1, D1, A2, B2, C2, D2, oee, oeo, ooe, oos);
        o0.z = oee; o0.w = oeo; o1.z = ooe; o1.w = oos;
    }
}

__global__ __launch_bounds__(256)
void dwt_fuse_idwt_concat_kernel(const float* __restrict__ x1,
                                 const float* __restrict__ x2,
                                 float* __restrict__ out) {
    // One thread handles 4 rows x 4 cols: two vertically-adjacent row-pairs
    // at the same float4 column. All 8 loads issued up-front for MLP; every
    // load/store instruction's 64 lanes cover a contiguous 1 KiB row segment.
    // idx -> (bc, hq, w4); W/4 = 64 float4-cols, H/4 = 64 row-quads,
    // bc in [0, 512). Total threads = 512*64*64 = 2,097,152.
    const int idx = blockIdx.x * blockDim.x + threadIdx.x;

    const int w4 = idx & 63;         // float4 column index
    const int t  = idx >> 6;
    const int hq = t & 63;           // row-quad index (4 rows each)
    const int bc = t >> 6;           // b*64 + c, in [0, 512)

    // input base: element offset of (bc, 4*hq, 4*w4); row stride = 256 floats
    const int inBase = ((bc << 8) + (hq << 2)) * 256 + (w4 << 2);

    const f32x4 a0 = ntload4(x1 + inBase);          // x1 row 0
    const f32x4 a1 = ntload4(x1 + inBase + 256);    // x1 row 1
    const f32x4 a2 = ntload4(x1 + inBase + 512);    // x1 row 2
    const f32x4 a3 = ntload4(x1 + inBase + 768);    // x1 row 3
    const f32x4 b0 = ntload4(x2 + inBase);          // x2 row 0
    const f32x4 b1 = ntload4(x2 + inBase + 256);    // x2 row 1
    const f32x4 b2 = ntload4(x2 + inBase + 512);    // x2 row 2
    const f32x4 b3 = ntload4(x2 + inBase + 768);    // x2 row 3

    f32x4 o0, o1, o2, o3;
    process_rowpair(a0, a1, b0, b1, o0, o1);
    process_rowpair(a2, a3, b2, b3, o2, o3);

    // output: (8, 128, 256, 256); x_rec at channel c, x2 copy at channel 64+c
    const int b = bc >> 6;
    const int c = bc & 63;
    const int outBaseRec = ((((b << 7) + c) << 8) | (hq << 2)) * 256 + (w4 << 2);
    const int outBaseCpy = outBaseRec + (64 << 16);  // +64 channels * 256*256

    ntstore4(out + outBaseRec,        o0);
    ntstore4(out + outBaseRec + 256,  o1);
    ntstore4(out + outBaseRec + 512,  o2);
    ntstore4(out + outBaseRec + 768,  o3);
    ntstore4(out + outBaseCpy,        b0);   // x2 copy rows
    ntstore4(out + outBaseCpy + 256,  b1);
    ntstore4(out + outBaseCpy + 512,  b2);
    ntstore4(out + outBaseCpy + 768,  b3);
}

extern "C" void kernel_launch(void* const* d_in, const int* in_sizes, int n_in,
                              void* d_out, int out_size, void* d_ws, size_t ws_size,
                              hipStream_t stream) {
    const float* x1 = (const float*)d_in[0];
    const float* x2 = (const float*)d_in[1];
    float* out = (float*)d_out;

    const int total_threads = 8 * 64 * 64 * 64;   // 2,097,152
    const int block = 256;
    const int grid = total_threads / block;       // 8192

    dwt_fuse_idwt_concat_kernel<<<grid, block, 0, stream>>>(x1, x2, out);
}